// Round 1
// baseline (148.582 us; speedup 1.0000x reference)
//
#include <hip/hip_runtime.h>

#define N 4096
#define IN_DIM 6
#define HID 32
#define HEADS1 4
#define D1 (HEADS1*HID)   // 128
#define OUT_DIM 64
#define MAXNB 192         // Binomial(4096,0.01): mean ~41, std 6.4 -> 192 is >20 sigma

// A: hpre[i,t] = sum_k x[i,k]*W1[k,t], plus per-head e_src/e_dst dots.
// 2 rows per block. grid N/2, block 256.
__global__ void kA(const float* __restrict__ x,
                   const float* __restrict__ W1,
                   const float* __restrict__ a_src1,
                   const float* __restrict__ a_dst1,
                   float* __restrict__ hpre,
                   float* __restrict__ es1,
                   float* __restrict__ ed1) {
    int t  = threadIdx.x;
    int r  = t >> 7;               // row within block (0/1)
    int tt = t & 127;              // feature index
    int i  = blockIdx.x * 2 + r;
    __shared__ float xs[2][IN_DIM];
    if (tt < IN_DIM) xs[r][tt] = x[i*IN_DIM + tt];
    __syncthreads();
    float acc = 0.f;
    #pragma unroll
    for (int k = 0; k < IN_DIM; ++k)
        acc += xs[r][k] * W1[k*D1 + tt];
    hpre[(size_t)i*D1 + tt] = acc;
    // waves hold (r, head-pair); xor offsets <32 stay inside each 32-lane head group
    float ps = acc * a_src1[tt];
    float pd = acc * a_dst1[tt];
    #pragma unroll
    for (int off = 16; off >= 1; off >>= 1) {
        ps += __shfl_xor(ps, off, 64);
        pd += __shfl_xor(pd, off, 64);
    }
    if ((tt & 31) == 0) {
        int h = tt >> 5;
        es1[i*HEADS1 + h] = ps;
        ed1[i*HEADS1 + h] = pd;
    }
}

// B: fused CSR-build + logits + softmax + aggregate + ELU + (h1 @ W2) + es2/ed2.
// h1 never touches global memory. grid N, block 256.
__global__ void kB(const float* __restrict__ adj,
                   const float* __restrict__ hpre,
                   const float* __restrict__ es1,
                   const float* __restrict__ ed1,
                   const float* __restrict__ b1,
                   const float* __restrict__ W2,
                   const float* __restrict__ a_src2,
                   const float* __restrict__ a_dst2,
                   int* __restrict__ cnt, int* __restrict__ idxg,
                   float* __restrict__ h2pre,
                   float* __restrict__ es2, float* __restrict__ ed2) {
    int i = blockIdx.x;
    int t = threadIdx.x;            // 0..255
    __shared__ int   cL;
    __shared__ int   js[MAXNB];
    __shared__ float lg[HEADS1][MAXNB];   // logits, then exp(l-m) in place
    __shared__ float esi[HEADS1];
    __shared__ float sinv[HEADS1];
    __shared__ float part[128];
    __shared__ float h1s[D1];
    __shared__ float p2s[256];
    if (t == 0) cL = 0;
    if (t < HEADS1) esi[t] = es1[i*HEADS1 + t];
    __syncthreads();

    // --- scan adj row: build neighbor list AND logits in one pass ---
    const float4* row  = (const float4*)(adj + (size_t)i * N);   // 1024 float4, 4 iters/thread
    const float4* ed1v = (const float4*)ed1;                     // ed1 is [N][4], 16B aligned
    for (int k = t; k < N/4; k += 256) {
        float4 v = row[k];
        float f[4] = {v.x, v.y, v.z, v.w};
        #pragma unroll
        for (int q = 0; q < 4; ++q) {
            int j = k*4 + q;
            if (f[q] > 0.f || j == i) {
                int p = atomicAdd(&cL, 1);
                if (p < MAXNB) {
                    js[p] = j;
                    float4 e4 = ed1v[j];
                    float le[4] = {e4.x, e4.y, e4.z, e4.w};
                    #pragma unroll
                    for (int h = 0; h < HEADS1; ++h) {
                        float l = esi[h] + le[h];
                        lg[h][p] = (l > 0.f) ? l : 0.2f*l;   // leaky_relu 0.2
                    }
                }
            }
        }
    }
    __syncthreads();
    int c = min(cL, MAXNB);

    if (t >= 128) {
        // waves 2-3: persist CSR for kernel C while waves 0-1 run softmax
        if (t == 128) cnt[i] = c;
        for (int p = t - 128; p < c; p += 128) idxg[i*MAXNB + p] = js[p];
    } else {
        // waves 0-1: per-head max + exp + sum (exp stored in place, 1/s folded later)
        int h = t >> 5, lane = t & 31;
        float m = -1e30f;
        for (int p = lane; p < c; p += 32) m = fmaxf(m, lg[h][p]);
        #pragma unroll
        for (int off = 16; off >= 1; off >>= 1) m = fmaxf(m, __shfl_xor(m, off, 64));
        float s = 0.f;
        for (int p = lane; p < c; p += 32) {
            float e = __expf(lg[h][p] - m);
            lg[h][p] = e;
            s += e;
        }
        #pragma unroll
        for (int off = 16; off >= 1; off >>= 1) s += __shfl_xor(s, off, 64);
        if (lane == 0) sinv[h] = 1.f / s;
    }
    __syncthreads();

    // --- aggregate: 2 groups split the neighbor loop, halving its serial length ---
    int g = t >> 7, tt = t & 127, hh = (t & 127) >> 5;
    float acc = 0.f;
    for (int p = g; p < c; p += 2)
        acc += lg[hh][p] * hpre[(size_t)js[p]*D1 + tt];
    if (g == 1) part[tt] = acc;
    __syncthreads();
    if (g == 0) {
        acc += part[tt];
        float val = acc * sinv[hh] + b1[tt];
        h1s[tt] = (val > 0.f) ? val : expm1f(val);   // ELU (alpha=1)
    }
    __syncthreads();

    // --- layer-2 pre: h2 = h1s @ W2 (256 threads, 4 partials per output) ---
    int o = t & 63, q = t >> 6;
    float pa = 0.f;
    #pragma unroll
    for (int k = 0; k < 32; ++k) {
        int kk = q*32 + k;
        pa += h1s[kk] * W2[kk*OUT_DIM + o];
    }
    p2s[t] = pa;
    __syncthreads();
    if (t < 64) {
        float h2 = p2s[t] + p2s[t+64] + p2s[t+128] + p2s[t+192];
        h2pre[(size_t)i*OUT_DIM + t] = h2;
        float ps = h2 * a_src2[t];
        float pd = h2 * a_dst2[t];
        #pragma unroll
        for (int off = 32; off >= 1; off >>= 1) {
            ps += __shfl_xor(ps, off, 64);
            pd += __shfl_xor(pd, off, 64);
        }
        if (t == 0) { es2[i] = ps; ed2[i] = pd; }
    }
}

// C: layer-2 masked softmax + aggregate + bias. One exp pass, 1/s folded at the end.
// grid N, block 64 (1 wave).
__global__ void kC(const float* __restrict__ h2pre,
                   const float* __restrict__ es2,
                   const float* __restrict__ ed2,
                   const int* __restrict__ cnt,
                   const int* __restrict__ idxg,
                   const float* __restrict__ b2v,
                   float* __restrict__ out) {
    int i = blockIdx.x;
    int t = threadIdx.x;            // 0..63
    int c = cnt[i];
    __shared__ int   js[MAXNB];
    __shared__ float al[MAXNB];
    for (int p = t; p < c; p += 64) js[p] = idxg[i*MAXNB + p];
    __syncthreads();
    float esi = es2[i];
    float m = -1e30f;
    for (int p = t; p < c; p += 64) {
        float l = esi + ed2[js[p]];
        l = (l > 0.f) ? l : 0.2f*l;
        al[p] = l;
        m = fmaxf(m, l);
    }
    #pragma unroll
    for (int off = 32; off >= 1; off >>= 1) m = fmaxf(m, __shfl_xor(m, off, 64));
    __syncthreads();
    float s = 0.f;
    for (int p = t; p < c; p += 64) {
        float e = __expf(al[p] - m);
        al[p] = e;
        s += e;
    }
    #pragma unroll
    for (int off = 32; off >= 1; off >>= 1) s += __shfl_xor(s, off, 64);
    float inv = 1.f / s;
    __syncthreads();
    float acc = 0.f;
    for (int p = 0; p < c; ++p)
        acc += al[p] * h2pre[(size_t)js[p]*OUT_DIM + t];
    out[(size_t)i*OUT_DIM + t] = acc * inv + b2v[t];
}

extern "C" void kernel_launch(void* const* d_in, const int* in_sizes, int n_in,
                              void* d_out, int out_size, void* d_ws, size_t ws_size,
                              hipStream_t stream) {
    const float* x      = (const float*)d_in[0];
    const float* adj    = (const float*)d_in[1];
    const float* W1     = (const float*)d_in[2];
    const float* a_src1 = (const float*)d_in[3];
    const float* a_dst1 = (const float*)d_in[4];
    const float* b1     = (const float*)d_in[5];
    const float* W2     = (const float*)d_in[6];
    const float* a_src2 = (const float*)d_in[7];
    const float* a_dst2 = (const float*)d_in[8];
    const float* b2v    = (const float*)d_in[9];
    float* out = (float*)d_out;

    // workspace layout (fp32 words); h1 eliminated (lives in LDS inside kB)
    float* ws    = (float*)d_ws;
    float* hpre  = ws;                        // N*128
    float* h2pre = hpre  + (size_t)N*D1;      // N*64
    float* es1   = h2pre + (size_t)N*OUT_DIM; // N*4
    float* ed1   = es1   + (size_t)N*HEADS1;  // N*4  (16B-aligned for float4 loads)
    float* es2   = ed1   + (size_t)N*HEADS1;  // N
    float* ed2   = es2   + N;                 // N
    int*   cnt   = (int*)(ed2 + N);           // N
    int*   idxg  = cnt + N;                   // N*MAXNB

    kA<<<N/2, 256, 0, stream>>>(x, W1, a_src1, a_dst1, hpre, es1, ed1);
    kB<<<N,   256, 0, stream>>>(adj, hpre, es1, ed1, b1, W2, a_src2, a_dst2,
                                cnt, idxg, h2pre, es2, ed2);
    kC<<<N,    64, 0, stream>>>(h2pre, es2, ed2, cnt, idxg, b2v, out);
}

// Round 2
// 137.106 us; speedup vs baseline: 1.0837x; 1.0837x over previous
//
#include <hip/hip_runtime.h>

#define N 4096
#define IN_DIM 6
#define HID 32
#define HEADS1 4
#define D1 (HEADS1*HID)   // 128
#define OUT_DIM 64
#define MAXNB 192         // Binomial(4096,0.01): mean ~41, std 6.4 -> 192 is >20 sigma

// A: hpre[i,t] = sum_k x[i,k]*W1[k,t], plus per-head e_src/e_dst dots.
// 2 rows per block. grid N/2, block 256.
__global__ void kA(const float* __restrict__ x,
                   const float* __restrict__ W1,
                   const float* __restrict__ a_src1,
                   const float* __restrict__ a_dst1,
                   float* __restrict__ hpre,
                   float* __restrict__ es1,
                   float* __restrict__ ed1) {
    int t  = threadIdx.x;
    int r  = t >> 7;               // row within block (0/1)
    int tt = t & 127;              // feature index
    int i  = blockIdx.x * 2 + r;
    __shared__ float xs[2][IN_DIM];
    if (tt < IN_DIM) xs[r][tt] = x[i*IN_DIM + tt];
    __syncthreads();
    float acc = 0.f;
    #pragma unroll
    for (int k = 0; k < IN_DIM; ++k)
        acc += xs[r][k] * W1[k*D1 + tt];
    hpre[(size_t)i*D1 + tt] = acc;
    float ps = acc * a_src1[tt];
    float pd = acc * a_dst1[tt];
    #pragma unroll
    for (int off = 16; off >= 1; off >>= 1) {   // xor <32 stays inside each 32-lane head group
        ps += __shfl_xor(ps, off, 64);
        pd += __shfl_xor(pd, off, 64);
    }
    if ((tt & 31) == 0) {
        int h = tt >> 5;
        es1[i*HEADS1 + h] = ps;
        ed1[i*HEADS1 + h] = pd;
    }
}

// B: fused CSR-build + logits + softmax + aggregate + ELU + (h1 @ W2) + es2/ed2.
// grid N, block 512. All gather phases are one-latency-round parallel; aggregate
// is 4-way split + 4x unrolled for MLP.
__global__ __launch_bounds__(512) void kB(
                   const float* __restrict__ adj,
                   const float* __restrict__ hpre,
                   const float* __restrict__ es1,
                   const float* __restrict__ ed1,
                   const float* __restrict__ b1,
                   const float* __restrict__ W2,
                   const float* __restrict__ a_src2,
                   const float* __restrict__ a_dst2,
                   int* __restrict__ cnt, int* __restrict__ idxg,
                   float* __restrict__ h2pre,
                   float* __restrict__ es2, float* __restrict__ ed2) {
    int i = blockIdx.x;
    int t = threadIdx.x;            // 0..511
    __shared__ int   cL;
    __shared__ int   js[MAXNB];
    __shared__ float lg[HEADS1][MAXNB];   // logits, then exp(l-m) in place
    __shared__ float esi[HEADS1];
    __shared__ float sinv[HEADS1];
    __shared__ float part[3][D1];
    __shared__ float h1s[D1];
    __shared__ float p2s[512];
    if (t == 0) cL = 0;
    if (t < HEADS1) esi[t] = es1[i*HEADS1 + t];
    __syncthreads();

    // --- scan adj row: both float4 issued up front (one HBM/L3 latency round) ---
    const float4* row = (const float4*)(adj + (size_t)i * N);   // 1024 float4
    float4 v0 = row[t];
    float4 v1 = row[t + 512];
    float f[8] = {v0.x, v0.y, v0.z, v0.w, v1.x, v1.y, v1.z, v1.w};
    #pragma unroll
    for (int q = 0; q < 8; ++q) {
        int j = (q < 4) ? (t*4 + q) : (2048 + t*4 + (q - 4));
        if (f[q] > 0.f || j == i) {
            int p = atomicAdd(&cL, 1);
            if (p < MAXNB) js[p] = j;
        }
    }
    __syncthreads();
    int c = min(cL, MAXNB);

    // --- logits: one thread per neighbor (all gathers concurrent); CSR persist in parallel ---
    if (t < c) {
        int j = js[t];
        float4 e4 = ((const float4*)ed1)[j];   // ed1 is [N][4], 16B aligned
        float l0 = esi[0] + e4.x, l1 = esi[1] + e4.y,
              l2 = esi[2] + e4.z, l3 = esi[3] + e4.w;
        lg[0][t] = (l0 > 0.f) ? l0 : 0.2f*l0;
        lg[1][t] = (l1 > 0.f) ? l1 : 0.2f*l1;
        lg[2][t] = (l2 > 0.f) ? l2 : 0.2f*l2;
        lg[3][t] = (l3 > 0.f) ? l3 : 0.2f*l3;
    }
    if (t >= 256) {
        int p = t - 256;
        if (p == 0) cnt[i] = c;
        if (p < c) idxg[i*MAXNB + p] = js[p];
    }
    __syncthreads();

    // --- softmax: wave w handles head w (t<256) ---
    if (t < 256) {
        int h = t >> 6, l = t & 63;
        float m = -1e30f;
        for (int p = l; p < c; p += 64) m = fmaxf(m, lg[h][p]);
        #pragma unroll
        for (int off = 32; off >= 1; off >>= 1) m = fmaxf(m, __shfl_xor(m, off, 64));
        float s = 0.f;
        for (int p = l; p < c; p += 64) {
            float e = __expf(lg[h][p] - m);
            lg[h][p] = e;
            s += e;
        }
        #pragma unroll
        for (int off = 32; off >= 1; off >>= 1) s += __shfl_xor(s, off, 64);
        if (l == 0) sinv[h] = 1.f / s;
    }
    __syncthreads();

    // --- aggregate: 4-way p-split, 4x unrolled (4 gathers in flight per thread) ---
    int g = t >> 7, tt = t & 127, hh = tt >> 5;
    float acc = 0.f;
    int p = g;
    for (; p + 12 < c; p += 16) {
        int   j0 = js[p],      j1 = js[p+4],   j2 = js[p+8],   j3 = js[p+12];
        float w0 = lg[hh][p],  w1 = lg[hh][p+4], w2 = lg[hh][p+8], w3 = lg[hh][p+12];
        float x0 = hpre[(size_t)j0*D1 + tt];
        float x1 = hpre[(size_t)j1*D1 + tt];
        float x2 = hpre[(size_t)j2*D1 + tt];
        float x3 = hpre[(size_t)j3*D1 + tt];
        acc += w0*x0 + w1*x1 + w2*x2 + w3*x3;
    }
    for (; p < c; p += 4)
        acc += lg[hh][p] * hpre[(size_t)js[p]*D1 + tt];
    if (g) part[g-1][tt] = acc;
    __syncthreads();
    if (g == 0) {
        acc += part[0][tt] + part[1][tt] + part[2][tt];
        float val = acc * sinv[hh] + b1[tt];
        h1s[tt] = (val > 0.f) ? val : expm1f(val);   // ELU (alpha=1)
    }
    __syncthreads();

    // --- layer-2 pre: h2 = h1s @ W2, 8 partials per output column ---
    int o = t & 63, q = t >> 6;                // q = 0..7
    float pa = 0.f;
    #pragma unroll
    for (int k = 0; k < 16; ++k) {
        int kk = q*16 + k;
        pa += h1s[kk] * W2[kk*OUT_DIM + o];
    }
    p2s[t] = pa;
    __syncthreads();
    if (t < 64) {
        float h2 = 0.f;
        #pragma unroll
        for (int qq = 0; qq < 8; ++qq) h2 += p2s[t + 64*qq];
        h2pre[(size_t)i*OUT_DIM + t] = h2;
        float ps = h2 * a_src2[t];
        float pd = h2 * a_dst2[t];
        #pragma unroll
        for (int off = 32; off >= 1; off >>= 1) {
            ps += __shfl_xor(ps, off, 64);
            pd += __shfl_xor(pd, off, 64);
        }
        if (t == 0) { es2[i] = ps; ed2[i] = pd; }
    }
}

// C: layer-2 masked softmax + aggregate + bias. Parallel gathers, wave-0 softmax,
// 4-way x 4-unrolled aggregate. grid N, block 256.
__global__ __launch_bounds__(256) void kC(
                   const float* __restrict__ h2pre,
                   const float* __restrict__ es2,
                   const float* __restrict__ ed2,
                   const int* __restrict__ cnt,
                   const int* __restrict__ idxg,
                   const float* __restrict__ b2v,
                   float* __restrict__ out) {
    int i = blockIdx.x;
    int t = threadIdx.x;            // 0..255
    int c = cnt[i];                 // <= MAXNB <= 192 < 256
    __shared__ int   js[MAXNB];
    __shared__ float al[MAXNB];
    __shared__ float sinv_s;
    __shared__ float part[3][OUT_DIM];
    float esi = es2[i];
    if (t < c) {                    // one thread per neighbor: all gathers concurrent
        int j = idxg[i*MAXNB + t];
        js[t] = j;
        float l = esi + ed2[j];
        al[t] = (l > 0.f) ? l : 0.2f*l;
    }
    __syncthreads();
    if (t < 64) {                   // wave 0: max + exp + sum (<=3 elems/lane)
        float m = -1e30f;
        for (int p = t; p < c; p += 64) m = fmaxf(m, al[p]);
        #pragma unroll
        for (int off = 32; off >= 1; off >>= 1) m = fmaxf(m, __shfl_xor(m, off, 64));
        float s = 0.f;
        for (int p = t; p < c; p += 64) {
            float e = __expf(al[p] - m);
            al[p] = e;
            s += e;
        }
        #pragma unroll
        for (int off = 32; off >= 1; off >>= 1) s += __shfl_xor(s, off, 64);
        if (t == 0) sinv_s = 1.f / s;
    }
    __syncthreads();
    int g = t >> 6, o = t & 63;
    float acc = 0.f;
    int p = g;
    for (; p + 12 < c; p += 16) {
        int   j0 = js[p],    j1 = js[p+4],  j2 = js[p+8],  j3 = js[p+12];
        float w0 = al[p],    w1 = al[p+4],  w2 = al[p+8],  w3 = al[p+12];
        float x0 = h2pre[(size_t)j0*OUT_DIM + o];
        float x1 = h2pre[(size_t)j1*OUT_DIM + o];
        float x2 = h2pre[(size_t)j2*OUT_DIM + o];
        float x3 = h2pre[(size_t)j3*OUT_DIM + o];
        acc += w0*x0 + w1*x1 + w2*x2 + w3*x3;
    }
    for (; p < c; p += 4)
        acc += al[p] * h2pre[(size_t)js[p]*OUT_DIM + o];
    if (g) part[g-1][o] = acc;
    __syncthreads();
    if (g == 0) {
        acc += part[0][o] + part[1][o] + part[2][o];
        out[(size_t)i*OUT_DIM + o] = acc * sinv_s + b2v[o];
    }
}

extern "C" void kernel_launch(void* const* d_in, const int* in_sizes, int n_in,
                              void* d_out, int out_size, void* d_ws, size_t ws_size,
                              hipStream_t stream) {
    const float* x      = (const float*)d_in[0];
    const float* adj    = (const float*)d_in[1];
    const float* W1     = (const float*)d_in[2];
    const float* a_src1 = (const float*)d_in[3];
    const float* a_dst1 = (const float*)d_in[4];
    const float* b1     = (const float*)d_in[5];
    const float* W2     = (const float*)d_in[6];
    const float* a_src2 = (const float*)d_in[7];
    const float* a_dst2 = (const float*)d_in[8];
    const float* b2v    = (const float*)d_in[9];
    float* out = (float*)d_out;

    float* ws    = (float*)d_ws;
    float* hpre  = ws;                        // N*128
    float* h2pre = hpre  + (size_t)N*D1;      // N*64
    float* es1   = h2pre + (size_t)N*OUT_DIM; // N*4
    float* ed1   = es1   + (size_t)N*HEADS1;  // N*4  (16B-aligned for float4 loads)
    float* es2   = ed1   + (size_t)N*HEADS1;  // N
    float* ed2   = es2   + N;                 // N
    int*   cnt   = (int*)(ed2 + N);           // N
    int*   idxg  = cnt + N;                   // N*MAXNB

    kA<<<N/2, 256, 0, stream>>>(x, W1, a_src1, a_dst1, hpre, es1, ed1);
    kB<<<N,   512, 0, stream>>>(adj, hpre, es1, ed1, b1, W2, a_src2, a_dst2,
                                cnt, idxg, h2pre, es2, ed2);
    kC<<<N,   256, 0, stream>>>(h2pre, es2, ed2, cnt, idxg, b2v, out);
}